// Round 1
// baseline (1321.964 us; speedup 1.0000x reference)
//
#include <hip/hip_runtime.h>

#define V_ 10000
#define D_ 256
#define T_ 128
#define B_ 8
#define MS_ 4
#define S_ 5
#define EOS_ 4

typedef unsigned short b16_t;
typedef __attribute__((ext_vector_type(8))) short s16x8;
typedef __attribute__((ext_vector_type(8))) unsigned short u16x8;
typedef __attribute__((ext_vector_type(4))) float f32x4;

__device__ inline b16_t f2bf(float f) {
  union { float f; unsigned u; } v; v.f = f;
  unsigned r = v.u + 0x7FFFu + ((v.u >> 16) & 1u);
  return (b16_t)(r >> 16);
}
__device__ inline float bf2f(b16_t h) {
  union { unsigned u; float f; } v; v.u = ((unsigned)h) << 16; return v.f;
}
__device__ inline float sigm_(float x) { return 1.0f / (1.0f + __expf(-x)); }
__device__ inline float tanh_(float x) { return 2.0f / (1.0f + __expf(-2.0f * x)) - 1.0f; }

// ---------------- prep kernels ----------------
__global__ void k_cast(const float* __restrict__ src, b16_t* __restrict__ dst, int n) {
  int i = blockIdx.x * blockDim.x + threadIdx.x;
  int stride = gridDim.x * blockDim.x;
  for (; i < n; i += stride) dst[i] = f2bf(src[i]);
}

__global__ void k_gather_x(const int* __restrict__ x_ids, const float* __restrict__ emb,
                           b16_t* __restrict__ x_bf) {
  int bt = blockIdx.x, d = threadIdx.x;       // bt = b*T + t
  int b = bt >> 7, t = bt & 127;
  int tok = x_ids[b * (T_ + 2) + t + 1];      // y[b,t] = x_ids[b, t+WIN]
  x_bf[(size_t)bt * D_ + d] = f2bf(emb[(size_t)tok * D_ + d]);
}

__global__ void k_seq(const b16_t* __restrict__ x_bf, const float* __restrict__ y_start,
                      b16_t* __restrict__ seq_bf) {
  int m = blockIdx.x, d = threadIdx.x;        // m = t*B + b
  int t = m >> 3, b = m & 7;
  b16_t v = (t == 0) ? f2bf(y_start[d]) : x_bf[((size_t)b * T_ + (t - 1)) * D_ + d];
  seq_bf[(size_t)m * D_ + d] = v;
}

// ---------------- generic bf16 MFMA GEMM: C[M][N] = A[M][256] @ Bw[N][256]^T ----------------
__global__ __launch_bounds__(256) void k_gemm(const b16_t* __restrict__ A,
                                              const b16_t* __restrict__ Bw,
                                              const float* __restrict__ bias,
                                              float* __restrict__ C,
                                              int N, int act, int accum) {
  __shared__ b16_t As[64][264];
  __shared__ b16_t Bs[64][264];
  int tid = threadIdx.x;
  int rowBase = blockIdx.x * 64, colBase = blockIdx.y * 64;
  for (int i = tid; i < 64 * 32; i += 256) {
    int r = i >> 5, c = (i & 31) * 8;
    *(u16x8*)&As[r][c] = *(const u16x8*)(A + (size_t)(rowBase + r) * D_ + c);
    *(u16x8*)&Bs[r][c] = *(const u16x8*)(Bw + (size_t)(colBase + r) * D_ + c);
  }
  __syncthreads();
  int w = tid >> 6, l = tid & 63, lr = l & 15, kg = l >> 4;
  f32x4 acc[4] = {{0.f,0.f,0.f,0.f},{0.f,0.f,0.f,0.f},{0.f,0.f,0.f,0.f},{0.f,0.f,0.f,0.f}};
  for (int kk = 0; kk < 8; ++kk) {
    s16x8 a = *(const s16x8*)&As[w * 16 + lr][kk * 32 + kg * 8];
#pragma unroll
    for (int f = 0; f < 4; ++f) {
      s16x8 b = *(const s16x8*)&Bs[f * 16 + lr][kk * 32 + kg * 8];
      acc[f] = __builtin_amdgcn_mfma_f32_16x16x32_bf16(a, b, acc[f], 0, 0, 0);
    }
  }
#pragma unroll
  for (int f = 0; f < 4; ++f) {
#pragma unroll
    for (int r = 0; r < 4; ++r) {
      int m = rowBase + w * 16 + kg * 4 + r;
      int n = colBase + f * 16 + lr;
      float v = acc[f][r];
      if (bias) v += bias[n];
      if (act == 1) v = tanh_(v);
      size_t idx = (size_t)m * N + n;
      if (accum) C[idx] += v; else C[idx] = v;
    }
  }
}

// ---------------- encoder step ----------------
__global__ __launch_bounds__(256) void k_enc_step(const float* __restrict__ encX,
                                                  const float* __restrict__ Wh,
                                                  float* __restrict__ h_pp,
                                                  float* __restrict__ c_buf,
                                                  b16_t* __restrict__ droph_bf, int t) {
  __shared__ float Whs[32][257];
  __shared__ float hs[8][257];
  __shared__ float g_lds[8][32];
  int tid = threadIdx.x, blk = blockIdx.x;      // blk owns d in [8*blk, 8*blk+8)
  const float* h_read = h_pp + (size_t)(t & 1) * (B_ * D_);
  float* h_write = h_pp + (size_t)((t + 1) & 1) * (B_ * D_);
  for (int i = tid; i < 32 * 64; i += 256) {
    int rl = i >> 6, c4 = (i & 63) * 4;
    int gate = rl >> 3, dl = rl & 7;
    float4 v = *(const float4*)(Wh + (size_t)(gate * 256 + blk * 8 + dl) * 256 + c4);
    Whs[rl][c4] = v.x; Whs[rl][c4 + 1] = v.y; Whs[rl][c4 + 2] = v.z; Whs[rl][c4 + 3] = v.w;
  }
  for (int i = tid; i < 8 * 64; i += 256) {
    int b = i >> 6, c4 = (i & 63) * 4;
    float4 v = *(const float4*)(h_read + b * 256 + c4);
    hs[b][c4] = v.x; hs[b][c4 + 1] = v.y; hs[b][c4 + 2] = v.z; hs[b][c4 + 3] = v.w;
  }
  __syncthreads();
  int b = tid >> 5, rl = tid & 31;              // rl = gate*8 + dl
  float acc = encX[(size_t)(t * 8 + b) * 1024 + (rl >> 3) * 256 + blk * 8 + (rl & 7)];
#pragma unroll 8
  for (int k = 0; k < 256; ++k) acc += Whs[rl][k] * hs[b][k];
  g_lds[b][rl] = acc;
  __syncthreads();
  if (tid < 64) {
    int b2 = tid >> 3, dl = tid & 7;
    int d = blk * 8 + dl;
    float gi = g_lds[b2][dl], gf = g_lds[b2][8 + dl];
    float gg = g_lds[b2][16 + dl], go = g_lds[b2][24 + dl];
    float c = c_buf[b2 * 256 + d];
    float c2 = sigm_(gf) * c + sigm_(gi) * tanh_(gg);
    float h2 = sigm_(go) * tanh_(c2);
    c_buf[b2 * 256 + d] = c2;
    h_write[b2 * 256 + d] = h2;
    droph_bf[(size_t)(t * 8 + b2) * 256 + d] = f2bf(0.1f * h2);
  }
}

// ---------------- decoder ----------------
__global__ void k_dec_init(const float* __restrict__ hlin, b16_t* __restrict__ h0_bf,
                           b16_t* __restrict__ h1_bf, float* __restrict__ c0,
                           float* __restrict__ c1) {
  int p = blockIdx.x, d = threadIdx.x;
  h0_bf[(size_t)p * D_ + d] = f2bf(hlin[(size_t)p * 512 + d]);
  h1_bf[(size_t)p * D_ + d] = f2bf(hlin[(size_t)p * 512 + 256 + d]);
  c0[(size_t)p * D_ + d] = 0.f;
  c1[(size_t)p * D_ + d] = 0.f;
}

__global__ void k_seg(const b16_t* __restrict__ x_bf, const float* __restrict__ y_in0,
                      b16_t* __restrict__ seg_bf) {
  int ps = blockIdx.x, d = threadIdx.x;         // ps = p*S + s
  int p = ps / S_, s = ps % S_;
  int t = p >> 3, b = p & 7;
  b16_t v;
  if (s == 0) v = f2bf(y_in0[(size_t)p * D_ + d]);
  else {
    int tt = t + s - 1;
    v = (tt < T_) ? x_bf[((size_t)b * T_ + tt) * D_ + d] : (b16_t)0;
  }
  seg_bf[(size_t)ps * D_ + d] = v;
}

__global__ void k_cell(const float* __restrict__ G, const float* __restrict__ X0,
                       float* __restrict__ cst, b16_t* __restrict__ h_bf,
                       b16_t* __restrict__ dec_out, int s) {
  int p = blockIdx.x, d = threadIdx.x;
  const float* g = G + (size_t)p * 1024;
  float gi = g[d], gf = g[256 + d], gg = g[512 + d], go = g[768 + d];
  if (X0) {
    const float* x = X0 + ((size_t)p * S_ + s) * 1024;
    gi += x[d]; gf += x[256 + d]; gg += x[512 + d]; go += x[768 + d];
  }
  float c = cst[(size_t)p * D_ + d];
  float c2 = sigm_(gf) * c + sigm_(gi) * tanh_(gg);
  float h2 = sigm_(go) * tanh_(c2);
  cst[(size_t)p * D_ + d] = c2;
  h_bf[(size_t)p * D_ + d] = f2bf(h2);
  if (dec_out) dec_out[((size_t)p * S_ + s) * D_ + d] = f2bf(h2);
}

// ---------------- logits + fused sum(exp) ----------------
__global__ __launch_bounds__(256) void k_logits(const b16_t* __restrict__ Abf,
                                                const b16_t* __restrict__ emb_bf,
                                                const float* __restrict__ out_b,
                                                float* __restrict__ sumexp) {
  __shared__ b16_t As[64][264];
  __shared__ b16_t Bs[64][264];
  int tid = threadIdx.x;
  int rowBase = blockIdx.x * 64, colBase = blockIdx.y * 64;
  for (int i = tid; i < 64 * 32; i += 256) {
    int r = i >> 5, c = (i & 31) * 8;
    *(u16x8*)&As[r][c] = *(const u16x8*)(Abf + (size_t)(rowBase + r) * D_ + c);
    int vrow = colBase + r;
    u16x8 bv = {0,0,0,0,0,0,0,0};
    if (vrow < V_) bv = *(const u16x8*)(emb_bf + (size_t)vrow * D_ + c);
    *(u16x8*)&Bs[r][c] = bv;
  }
  __syncthreads();
  int w = tid >> 6, l = tid & 63, lr = l & 15, kg = l >> 4;
  f32x4 acc[4] = {{0.f,0.f,0.f,0.f},{0.f,0.f,0.f,0.f},{0.f,0.f,0.f,0.f},{0.f,0.f,0.f,0.f}};
  for (int kk = 0; kk < 8; ++kk) {
    s16x8 a = *(const s16x8*)&As[w * 16 + lr][kk * 32 + kg * 8];
#pragma unroll
    for (int f = 0; f < 4; ++f) {
      s16x8 b = *(const s16x8*)&Bs[f * 16 + lr][kk * 32 + kg * 8];
      acc[f] = __builtin_amdgcn_mfma_f32_16x16x32_bf16(a, b, acc[f], 0, 0, 0);
    }
  }
#pragma unroll
  for (int r = 0; r < 4; ++r) {
    float rs = 0.f;
#pragma unroll
    for (int f = 0; f < 4; ++f) {
      int n = colBase + f * 16 + lr;
      if (n < V_) rs += __expf(acc[f][r] + out_b[n]);
    }
    for (int m = 1; m < 16; m <<= 1) rs += __shfl_xor(rs, m, 64);
    if (lr == 0) atomicAdd(&sumexp[rowBase + w * 16 + kg * 4 + r], rs);
  }
}

// ---------------- target / EOS logit extraction ----------------
__global__ void k_extract(const b16_t* __restrict__ dec_h, const b16_t* __restrict__ emb_bf,
                          const float* __restrict__ out_b, const int* __restrict__ x_ids,
                          float* __restrict__ tl, float* __restrict__ el) {
  int p = blockIdx.x, lane = threadIdx.x;       // 64 threads
  int t = p >> 3, b = p & 7;
  for (int s = 0; s < S_; ++s) {
    const b16_t* hr = dec_h + ((size_t)p * S_ + s) * D_;
    float hv[4];
#pragma unroll
    for (int j = 0; j < 4; ++j) hv[j] = bf2f(hr[lane * 4 + j]);
    if (s < MS_) {
      int pos = t + s; if (pos > T_ - 1) pos = T_ - 1;
      int tok = x_ids[b * (T_ + 2) + pos + 1];
      const b16_t* er = emb_bf + (size_t)tok * D_;
      float ps = 0.f;
#pragma unroll
      for (int j = 0; j < 4; ++j) ps += hv[j] * bf2f(er[lane * 4 + j]);
      for (int m = 1; m < 64; m <<= 1) ps += __shfl_xor(ps, m, 64);
      if (lane == 0) tl[p * MS_ + s] = ps + out_b[tok];
    }
    if (s >= 1) {
      const b16_t* er = emb_bf + (size_t)EOS_ * D_;
      float ps = 0.f;
#pragma unroll
      for (int j = 0; j < 4; ++j) ps += hv[j] * bf2f(er[lane * 4 + j]);
      for (int m = 1; m < 64; m <<= 1) ps += __shfl_xor(ps, m, 64);
      if (lane == 0) el[p * MS_ + (s - 1)] = ps + out_b[EOS_];
    }
  }
}

// ---------------- final: log-probs, DP, loss ----------------
__global__ __launch_bounds__(256) void k_final(const float* __restrict__ sumexp,
                                               const float* __restrict__ tl,
                                               const float* __restrict__ el,
                                               const int* __restrict__ lens,
                                               float* __restrict__ out) {
  __shared__ float logpy[T_][S_][B_];           // [t][k][b], k=1..4 used
  __shared__ float alpha[T_ + 1][B_];
  int tid = threadIdx.x;
  for (int p = tid; p < T_ * B_; p += 256) {
    int t = p >> 3, b = p & 7;
    float lz[S_];
#pragma unroll
    for (int s = 0; s < S_; ++s) lz[s] = __logf(sumexp[p * S_ + s]);
    float cum = 0.f, cums[MS_];
#pragma unroll
    for (int s = 0; s < MS_; ++s) {
      float tlp = tl[p * MS_ + s] - lz[s];
      if (t + s < T_) cum += tlp;
      cums[s] = cum;
    }
#pragma unroll
    for (int k = 1; k <= MS_; ++k) {
      float bv = -1000000.0f;
      if (t + k <= T_) bv = cums[k - 1] + (el[p * MS_ + (k - 1)] - lz[k]);
      logpy[t][k][b] = bv;
    }
  }
  __syncthreads();
  if (tid < B_) {
    int b = tid;
    alpha[0][b] = 0.f;
    for (int j = 1; j <= T_; ++j) {
      float vs[MS_], vmax = -1e30f;
#pragma unroll
      for (int k = 1; k <= MS_; ++k) {
        float vv = -2000000.0f;
        if (j - k >= 0) vv = alpha[j - k][b] + logpy[j - k][k][b];
        vs[k - 1] = vv;
        if (vv > vmax) vmax = vv;
      }
      float ssum = 0.f;
#pragma unroll
      for (int k = 0; k < MS_; ++k) ssum += __expf(vs[k] - vmax);
      alpha[j][b] = vmax + __logf(ssum);
    }
  }
  __syncthreads();
  if (tid == 0) {
    float num = 0.f, den = 0.f;
    for (int b = 0; b < B_; ++b) { num += alpha[lens[b]][b]; den += (float)lens[b]; }
    out[0] = -num / den;
  }
}

// ---------------- host ----------------
extern "C" void kernel_launch(void* const* d_in, const int* in_sizes, int n_in,
                              void* d_out, int out_size, void* d_ws, size_t ws_size,
                              hipStream_t stream) {
  const int* x_ids   = (const int*)d_in[0];
  const int* lens    = (const int*)d_in[1];
  const float* emb   = (const float*)d_in[2];
  const float* y_st  = (const float*)d_in[3];
  const float* cWi   = (const float*)d_in[4];
  const float* cWh   = (const float*)d_in[5];
  const float* cb    = (const float*)d_in[6];
  const float* y0W   = (const float*)d_in[7];
  const float* y0b   = (const float*)d_in[8];
  const float* hlW   = (const float*)d_in[9];
  const float* hlb   = (const float*)d_in[10];
  const float* l0Wi  = (const float*)d_in[11];
  const float* l0Wh  = (const float*)d_in[12];
  const float* l0b   = (const float*)d_in[13];
  const float* l1Wi  = (const float*)d_in[14];
  const float* l1Wh  = (const float*)d_in[15];
  const float* l1b   = (const float*)d_in[16];
  const float* outb  = (const float*)d_in[17];
  float* out = (float*)d_out;
  (void)in_sizes; (void)n_in; (void)out_size; (void)ws_size;

  char* ws = (char*)d_ws;
  size_t cur = 0;
  auto alloc = [&](size_t bytes) { size_t o = cur; cur += (bytes + 255) & ~(size_t)255; return o; };
  b16_t* emb_bf    = (b16_t*)(ws + alloc((size_t)V_ * D_ * 2));
  b16_t* cWi_bf    = (b16_t*)(ws + alloc(1024 * 256 * 2));
  b16_t* y0W_bf    = (b16_t*)(ws + alloc(256 * 256 * 2));
  b16_t* hlW_bf    = (b16_t*)(ws + alloc(512 * 256 * 2));
  b16_t* l0Wi_bf   = (b16_t*)(ws + alloc(1024 * 256 * 2));
  b16_t* l0Wh_bf   = (b16_t*)(ws + alloc(1024 * 256 * 2));
  b16_t* l1Wi_bf   = (b16_t*)(ws + alloc(1024 * 256 * 2));
  b16_t* l1Wh_bf   = (b16_t*)(ws + alloc(1024 * 256 * 2));
  b16_t* x_bf      = (b16_t*)(ws + alloc((size_t)B_ * T_ * D_ * 2));
  b16_t* seq_bf    = (b16_t*)(ws + alloc(1024 * 256 * 2));
  float* encX      = (float*)(ws + alloc((size_t)1024 * 1024 * 4));
  float* h_pp      = (float*)(ws + alloc(2 * B_ * D_ * 4));
  float* c_buf     = (float*)(ws + alloc(B_ * D_ * 4));
  b16_t* droph_bf  = (b16_t*)(ws + alloc(1024 * 256 * 2));
  float* y_in0     = (float*)(ws + alloc(1024 * 256 * 4));
  float* hlin_o    = (float*)(ws + alloc(1024 * 512 * 4));
  b16_t* seg_bf    = (b16_t*)(ws + alloc((size_t)5120 * 256 * 2));
  float* X0        = (float*)(ws + alloc((size_t)5120 * 1024 * 4));
  b16_t* h0_bf     = (b16_t*)(ws + alloc(1024 * 256 * 2));
  b16_t* h1_bf     = (b16_t*)(ws + alloc(1024 * 256 * 2));
  float* c0        = (float*)(ws + alloc(1024 * 256 * 4));
  float* c1        = (float*)(ws + alloc(1024 * 256 * 4));
  float* G0        = (float*)(ws + alloc((size_t)1024 * 1024 * 4));
  float* G1        = (float*)(ws + alloc((size_t)1024 * 1024 * 4));
  b16_t* dec_h_bf  = (b16_t*)(ws + alloc((size_t)5120 * 256 * 2));
  float* sumexp    = (float*)(ws + alloc(5120 * 4));
  float* tl        = (float*)(ws + alloc(1024 * MS_ * 4));
  float* el        = (float*)(ws + alloc(1024 * MS_ * 4));

  hipMemsetAsync(h_pp, 0, 2 * B_ * D_ * 4, stream);
  hipMemsetAsync(c_buf, 0, B_ * D_ * 4, stream);
  hipMemsetAsync(sumexp, 0, 5120 * 4, stream);

  k_cast<<<64, 256, 0, stream>>>(emb, emb_bf, V_ * D_);
  k_cast<<<32, 256, 0, stream>>>(cWi, cWi_bf, 1024 * 256);
  k_cast<<<16, 256, 0, stream>>>(y0W, y0W_bf, 256 * 256);
  k_cast<<<16, 256, 0, stream>>>(hlW, hlW_bf, 512 * 256);
  k_cast<<<32, 256, 0, stream>>>(l0Wi, l0Wi_bf, 1024 * 256);
  k_cast<<<32, 256, 0, stream>>>(l0Wh, l0Wh_bf, 1024 * 256);
  k_cast<<<32, 256, 0, stream>>>(l1Wi, l1Wi_bf, 1024 * 256);
  k_cast<<<32, 256, 0, stream>>>(l1Wh, l1Wh_bf, 1024 * 256);
  k_gather_x<<<B_ * T_, 256, 0, stream>>>(x_ids, emb, x_bf);
  k_seq<<<1024, 256, 0, stream>>>(x_bf, y_st, seq_bf);

  // encX = seq @ cell_Wi^T + cell_b   (M=1024, N=1024)
  k_gemm<<<dim3(16, 16), 256, 0, stream>>>(seq_bf, cWi_bf, cb, encX, 1024, 0, 0);

  for (int t = 0; t < T_; ++t)
    k_enc_step<<<32, 256, 0, stream>>>(encX, cWh, h_pp, c_buf, droph_bf, t);

  // y_in0 = drop_h @ yin0_W^T + yin0_b   (N=256)
  k_gemm<<<dim3(16, 4), 256, 0, stream>>>(droph_bf, y0W_bf, y0b, y_in0, 256, 0, 0);
  // hlin = tanh(drop_h @ hlin_W^T + hlin_b)   (N=512)
  k_gemm<<<dim3(16, 8), 256, 0, stream>>>(droph_bf, hlW_bf, hlb, hlin_o, 512, 1, 0);
  k_dec_init<<<1024, 256, 0, stream>>>(hlin_o, h0_bf, h1_bf, c0, c1);
  k_seg<<<5120, 256, 0, stream>>>(x_bf, y_in0, seg_bf);
  // X0 = seg @ l0_Wi^T + l0_b   (M=5120, N=1024)
  k_gemm<<<dim3(80, 16), 256, 0, stream>>>(seg_bf, l0Wi_bf, l0b, X0, 1024, 0, 0);

  for (int s = 0; s < S_; ++s) {
    k_gemm<<<dim3(16, 16), 256, 0, stream>>>(h0_bf, l0Wh_bf, nullptr, G0, 1024, 0, 0);
    k_cell<<<1024, 256, 0, stream>>>(G0, X0, c0, h0_bf, nullptr, s);
    k_gemm<<<dim3(16, 16), 256, 0, stream>>>(h0_bf, l1Wi_bf, l1b, G1, 1024, 0, 0);
    k_gemm<<<dim3(16, 16), 256, 0, stream>>>(h1_bf, l1Wh_bf, nullptr, G1, 1024, 0, 1);
    k_cell<<<1024, 256, 0, stream>>>(G1, nullptr, c1, h1_bf, dec_h_bf, s);
  }

  k_logits<<<dim3(80, 157), 256, 0, stream>>>(dec_h_bf, emb_bf, outb, sumexp);
  k_extract<<<1024, 64, 0, stream>>>(dec_h_bf, emb_bf, outb, x_ids, tl, el);
  k_final<<<1, 256, 0, stream>>>(sumexp, tl, el, lens, out);
}

// Round 2
// 992.476 us; speedup vs baseline: 1.3320x; 1.3320x over previous
//
#include <hip/hip_runtime.h>

#define V_ 10000
#define D_ 256
#define T_ 128
#define B_ 8
#define MS_ 4
#define S_ 5
#define EOS_ 4

typedef unsigned short b16_t;
typedef __attribute__((ext_vector_type(8))) short s16x8;
typedef __attribute__((ext_vector_type(8))) unsigned short u16x8;
typedef __attribute__((ext_vector_type(4))) float f32x4;
typedef __attribute__((ext_vector_type(2))) _Float16 h16x2;

__device__ inline b16_t f2bf(float f) {
  union { float f; unsigned u; } v; v.f = f;
  unsigned r = v.u + 0x7FFFu + ((v.u >> 16) & 1u);
  return (b16_t)(r >> 16);
}
__device__ inline float bf2f(b16_t h) {
  union { unsigned u; float f; } v; v.u = ((unsigned)h) << 16; return v.f;
}
__device__ inline float sigm_(float x) { return 1.0f / (1.0f + __expf(-x)); }
__device__ inline float tanh_(float x) { return 2.0f / (1.0f + __expf(-2.0f * x)) - 1.0f; }
__device__ inline h16x2 bch(unsigned u) { return __builtin_bit_cast(h16x2, u); }
__device__ inline unsigned pkh(float a, float b) {
  h16x2 v; v.x = (_Float16)a; v.y = (_Float16)b;
  return __builtin_bit_cast(unsigned, v);
}

#if __has_builtin(__builtin_amdgcn_fdot2)
#define FDOT2(a, b, c) __builtin_amdgcn_fdot2((a), (b), (c), false)
#else
#define FDOT2(a, b, c) ((c) + (float)(a).x * (float)(b).x + (float)(a).y * (float)(b).y)
#endif

// ---------------- prep: all weight casts in one kernel ----------------
__device__ inline void cvt4(const float* __restrict__ s, b16_t* __restrict__ d) {
  float4 v = *(const float4*)s;
  ushort4 o = { f2bf(v.x), f2bf(v.y), f2bf(v.z), f2bf(v.w) };
  *(ushort4*)d = o;
}

__global__ void k_prep(const float* __restrict__ emb, const float* __restrict__ cWi,
                       const float* __restrict__ y0W, const float* __restrict__ hlW,
                       const float* __restrict__ l0Wi, const float* __restrict__ l0Wh,
                       const float* __restrict__ l1Wi, const float* __restrict__ l1Wh,
                       const float* __restrict__ cWh,
                       b16_t* __restrict__ emb_bf, b16_t* __restrict__ cWi_bf,
                       b16_t* __restrict__ y0W_bf, b16_t* __restrict__ hlW_bf,
                       b16_t* __restrict__ l0Wi_bf, b16_t* __restrict__ l0Wh_bf,
                       b16_t* __restrict__ Wcat_bf, unsigned* __restrict__ Whf) {
  for (long i = (long)blockIdx.x * blockDim.x + threadIdx.x; i < 1082368L;
       i += (long)gridDim.x * blockDim.x) {
    if (i < 640000L) { cvt4(emb + i * 4, emb_bf + i * 4); }
    else if (i < 705536L) { long j = i - 640000L; cvt4(cWi + j * 4, cWi_bf + j * 4); }
    else if (i < 721920L) { long j = i - 705536L; cvt4(y0W + j * 4, y0W_bf + j * 4); }
    else if (i < 754688L) { long j = i - 721920L; cvt4(hlW + j * 4, hlW_bf + j * 4); }
    else if (i < 820224L) { long j = i - 754688L; cvt4(l0Wi + j * 4, l0Wi_bf + j * 4); }
    else if (i < 885760L) { long j = i - 820224L; cvt4(l0Wh + j * 4, l0Wh_bf + j * 4); }
    else if (i < 1016832L) {
      long j = (i - 885760L) * 4;
      long n = j >> 9; int k = (int)(j & 511);
      const float* src = (k < 256) ? (l1Wi + n * 256 + k) : (l1Wh + n * 256 + (k - 256));
      cvt4(src, Wcat_bf + j);
    } else {
      long j = i - 1016832L;
      float4 v = *(const float4*)(cWh + j * 4);
      Whf[2 * j] = pkh(v.x, v.y);
      Whf[2 * j + 1] = pkh(v.z, v.w);
    }
  }
}

__global__ void k_gather_x(const int* __restrict__ x_ids, const float* __restrict__ emb,
                           b16_t* __restrict__ x_bf) {
  int bt = blockIdx.x, d = threadIdx.x;       // bt = b*T + t
  int b = bt >> 7, t = bt & 127;
  int tok = x_ids[b * (T_ + 2) + t + 1];
  x_bf[(size_t)bt * D_ + d] = f2bf(emb[(size_t)tok * D_ + d]);
}

__global__ void k_seq(const b16_t* __restrict__ x_bf, const float* __restrict__ y_start,
                      b16_t* __restrict__ seq_bf) {
  int m = blockIdx.x, d = threadIdx.x;        // m = t*B + b
  int t = m >> 3, b = m & 7;
  b16_t v = (t == 0) ? f2bf(y_start[d]) : x_bf[((size_t)b * T_ + (t - 1)) * D_ + d];
  seq_bf[(size_t)m * D_ + d] = v;
}

// ---------------- generic bf16 MFMA GEMM: C[M][N] = A[M][256] @ Bw[N][256]^T ----------------
__global__ __launch_bounds__(256) void k_gemm(const b16_t* __restrict__ A,
                                              const b16_t* __restrict__ Bw,
                                              const float* __restrict__ bias,
                                              float* __restrict__ C,
                                              int N, int act, int obf) {
  __shared__ b16_t As[64][264];
  __shared__ b16_t Bs[64][264];
  int tid = threadIdx.x;
  int rowBase = blockIdx.x * 64, colBase = blockIdx.y * 64;
  for (int i = tid; i < 64 * 32; i += 256) {
    int r = i >> 5, c = (i & 31) * 8;
    *(u16x8*)&As[r][c] = *(const u16x8*)(A + (size_t)(rowBase + r) * D_ + c);
    *(u16x8*)&Bs[r][c] = *(const u16x8*)(Bw + (size_t)(colBase + r) * D_ + c);
  }
  __syncthreads();
  int w = tid >> 6, l = tid & 63, lr = l & 15, kg = l >> 4;
  f32x4 acc[4] = {{0.f,0.f,0.f,0.f},{0.f,0.f,0.f,0.f},{0.f,0.f,0.f,0.f},{0.f,0.f,0.f,0.f}};
  for (int kk = 0; kk < 8; ++kk) {
    s16x8 a = *(const s16x8*)&As[w * 16 + lr][kk * 32 + kg * 8];
#pragma unroll
    for (int f = 0; f < 4; ++f) {
      s16x8 b = *(const s16x8*)&Bs[f * 16 + lr][kk * 32 + kg * 8];
      acc[f] = __builtin_amdgcn_mfma_f32_16x16x32_bf16(a, b, acc[f], 0, 0, 0);
    }
  }
#pragma unroll
  for (int f = 0; f < 4; ++f) {
#pragma unroll
    for (int r = 0; r < 4; ++r) {
      int m = rowBase + w * 16 + kg * 4 + r;
      int n = colBase + f * 16 + lr;
      float v = acc[f][r];
      if (bias) v += bias[n];
      if (act == 1) v = tanh_(v);
      size_t idx = (size_t)m * N + n;
      if (obf) ((b16_t*)C)[idx] = f2bf(v); else C[idx] = v;
    }
  }
}

// ---------------- persistent encoder: 16 blocks = 8 batches x 2 halves ----------------
__global__ __launch_bounds__(512, 2) void k_encoder(
    const unsigned* __restrict__ Whf,   // [1024][128] f16-pair packed
    const float* __restrict__ encX,     // [1024][1024] (seq@Wi^T + b)
    unsigned* __restrict__ hglob,       // [129][8][128] dwords of f16 pairs, slot 0 zeroed
    int* __restrict__ flags,            // [128][8] zeroed
    b16_t* __restrict__ droph) {        // [1024][256] bf16 of 0.1*h
  int blk = blockIdx.x, batch = blk >> 1, half = blk & 1;
  int tid = threadIdx.x;
  int gate = tid >> 7, dl = tid & 127;
  int dim = half * 128 + dl;
  int row = gate * 256 + dim;
  h16x2 wv[128];
  {
    const uint4* ws4 = (const uint4*)(Whf + (size_t)row * 128);
#pragma unroll
    for (int i = 0; i < 32; ++i) {
      uint4 v = ws4[i];
      wv[4 * i + 0] = bch(v.x); wv[4 * i + 1] = bch(v.y);
      wv[4 * i + 2] = bch(v.z); wv[4 * i + 3] = bch(v.w);
    }
  }
  __shared__ float gl[512];
  __shared__ unsigned hh[64];
  float c = 0.f;
#pragma unroll 1
  for (int t = 0; t < 128; ++t) {
    const uint4* hp = (const uint4*)(hglob + ((size_t)t * 8 + batch) * 128);
    float a0 = encX[((size_t)t * 8 + batch) * 1024 + row];
    float a1 = 0.f, a2 = 0.f, a3 = 0.f;
#pragma unroll
    for (int i = 0; i < 32; ++i) {
      uint4 hv = hp[i];
      a0 = FDOT2(bch(hv.x), wv[4 * i + 0], a0);
      a1 = FDOT2(bch(hv.y), wv[4 * i + 1], a1);
      a2 = FDOT2(bch(hv.z), wv[4 * i + 2], a2);
      a3 = FDOT2(bch(hv.w), wv[4 * i + 3], a3);
    }
    gl[tid] = (a0 + a1) + (a2 + a3);
    __syncthreads();
    if (tid < 128) {
      float gi = gl[tid], gf = gl[128 + tid], gg = gl[256 + tid], go = gl[384 + tid];
      float c2 = sigm_(gf) * c + sigm_(gi) * tanh_(gg);
      float h2 = sigm_(go) * tanh_(c2);
      c = c2;
      droph[((size_t)(t * 8 + batch)) * 256 + dim] = f2bf(0.1f * h2);
      ((_Float16*)hh)[tid] = (_Float16)h2;
    }
    __syncthreads();
    if (tid < 64)
      __hip_atomic_store(&hglob[((size_t)(t + 1) * 8 + batch) * 128 + half * 64 + tid],
                         hh[tid], __ATOMIC_RELAXED, __HIP_MEMORY_SCOPE_AGENT);
    __syncthreads();
    if (tid == 0) {
      __threadfence();
      __hip_atomic_fetch_add(&flags[t * 8 + batch], 1, __ATOMIC_ACQ_REL,
                             __HIP_MEMORY_SCOPE_AGENT);
      while (__hip_atomic_load(&flags[t * 8 + batch], __ATOMIC_ACQUIRE,
                               __HIP_MEMORY_SCOPE_AGENT) < 2)
        __builtin_amdgcn_s_sleep(1);
      __threadfence();
    }
    __syncthreads();
  }
}

// ---------------- seg build ----------------
__global__ void k_seg(const b16_t* __restrict__ x_bf, const b16_t* __restrict__ y_in0_bf,
                      b16_t* __restrict__ seg_bf) {
  int ps = blockIdx.x, d = threadIdx.x;         // ps = p*S + s
  int p = ps / S_, s = ps % S_;
  int t = p >> 3, b = p & 7;
  b16_t v;
  if (s == 0) v = y_in0_bf[(size_t)p * D_ + d];
  else {
    int tt = t + s - 1;
    v = (tt < T_) ? x_bf[((size_t)b * T_ + tt) * D_ + d] : (b16_t)0;
  }
  seg_bf[(size_t)ps * D_ + d] = v;
}

// ---------------- fused decoder step: full-row gates GEMM + LSTM cell ----------------
template <int K, int PHASE>
__global__ __launch_bounds__(512, 2) void k_dec_step(
    b16_t* __restrict__ hcat,           // [1024][512] : [h0 | h1] bf16
    const b16_t* __restrict__ Wbf,      // [1024][K]
    const float* __restrict__ X0,       // phase0: [5120][1024], else null
    const float* __restrict__ bias,     // phase1: l1_b
    float* __restrict__ cst,            // c state [1024][256]
    b16_t* __restrict__ dec_out,        // phase1: dec_h [5120][256]
    int s) {
  __shared__ b16_t As[16][(K == 256) ? 264 : 520];
  __shared__ float gacc[16][1028];
  int tid = threadIdx.x;
  int R0 = blockIdx.x * 16;
  constexpr int CH = K / 8;
  for (int i = tid; i < 16 * CH; i += 512) {
    int r = i / CH, cc = (i % CH) * 8;
    *(u16x8*)&As[r][cc] = *(const u16x8*)(hcat + (size_t)(R0 + r) * 512 + cc);
  }
  __syncthreads();
  int w = tid >> 6, l = tid & 63, lr = l & 15, kg = l >> 4;
  int g = w >> 1, ch = w & 1;
  constexpr int NK = K / 32;
  s16x8 af[NK];
#pragma unroll
  for (int kk = 0; kk < NK; ++kk) af[kk] = *(const s16x8*)&As[lr][kk * 32 + kg * 8];
  int ncol0 = g * 256 + ch * 128;
  f32x4 acc[8];
#pragma unroll
  for (int nt = 0; nt < 8; ++nt) acc[nt] = f32x4{0.f, 0.f, 0.f, 0.f};
#pragma unroll
  for (int nt = 0; nt < 8; ++nt) {
    int n = ncol0 + nt * 16 + lr;
    const b16_t* bp = Wbf + (size_t)n * K + kg * 8;
#pragma unroll
    for (int kk = 0; kk < NK; ++kk) {
      s16x8 bf = *(const s16x8*)(bp + kk * 32);
      acc[nt] = __builtin_amdgcn_mfma_f32_16x16x32_bf16(af[kk], bf, acc[nt], 0, 0, 0);
    }
  }
#pragma unroll
  for (int nt = 0; nt < 8; ++nt)
#pragma unroll
    for (int r = 0; r < 4; ++r)
      gacc[kg * 4 + r][ncol0 + nt * 16 + lr] = acc[nt][r];
  __syncthreads();
  // cell epilogue: 16 rows x 256 dims over 512 threads
  int rr = tid >> 5, dq = tid & 31;
  int p = R0 + rr;
#pragma unroll
  for (int u = 0; u < 8; ++u) {
    int d = u * 32 + dq;
    float gi = gacc[rr][d], gf = gacc[rr][256 + d];
    float gg = gacc[rr][512 + d], go = gacc[rr][768 + d];
    if (PHASE == 0) {
      const float* xp = X0 + ((size_t)p * 5 + s) * 1024;
      gi += xp[d]; gf += xp[256 + d]; gg += xp[512 + d]; go += xp[768 + d];
    } else {
      gi += bias[d]; gf += bias[256 + d]; gg += bias[512 + d]; go += bias[768 + d];
    }
    float c = cst[(size_t)p * 256 + d];
    float c2 = sigm_(gf) * c + sigm_(gi) * tanh_(gg);
    float h2 = sigm_(go) * tanh_(c2);
    cst[(size_t)p * 256 + d] = c2;
    b16_t hb = f2bf(h2);
    if (PHASE == 0) hcat[(size_t)p * 512 + d] = hb;
    else {
      hcat[(size_t)p * 512 + 256 + d] = hb;
      dec_out[((size_t)p * 5 + s) * 256 + d] = hb;
    }
  }
}

// ---------------- logits + fused sum(exp): A-frags in regs, loop over V tiles ----------------
__global__ __launch_bounds__(256) void k_logits(const b16_t* __restrict__ Abf,
                                                const b16_t* __restrict__ emb_bf,
                                                const float* __restrict__ out_b,
                                                float* __restrict__ sumexp) {
  __shared__ b16_t As[64][264];
  __shared__ b16_t Bs[64][264];
  int tid = threadIdx.x;
  int rowBase = blockIdx.x * 64;
  int t0 = blockIdx.y * 20, t1 = (t0 + 20 < 157) ? (t0 + 20) : 157;
  for (int i = tid; i < 64 * 32; i += 256) {
    int r = i >> 5, c = (i & 31) * 8;
    *(u16x8*)&As[r][c] = *(const u16x8*)(Abf + (size_t)(rowBase + r) * D_ + c);
  }
  __syncthreads();
  int w = tid >> 6, l = tid & 63, lr = l & 15, kg = l >> 4;
  s16x8 af[8];
#pragma unroll
  for (int kk = 0; kk < 8; ++kk) af[kk] = *(const s16x8*)&As[w * 16 + lr][kk * 32 + kg * 8];
  float runsum[4] = {0.f, 0.f, 0.f, 0.f};
  for (int tile = t0; tile < t1; ++tile) {
    int colBase = tile * 64;
    __syncthreads();
    for (int i = tid; i < 64 * 32; i += 256) {
      int r = i >> 5, c = (i & 31) * 8;
      int vrow = colBase + r;
      u16x8 bv = {0, 0, 0, 0, 0, 0, 0, 0};
      if (vrow < V_) bv = *(const u16x8*)(emb_bf + (size_t)vrow * D_ + c);
      *(u16x8*)&Bs[r][c] = bv;
    }
    __syncthreads();
    f32x4 acc[4] = {{0.f,0.f,0.f,0.f},{0.f,0.f,0.f,0.f},{0.f,0.f,0.f,0.f},{0.f,0.f,0.f,0.f}};
#pragma unroll
    for (int kk = 0; kk < 8; ++kk) {
#pragma unroll
      for (int f = 0; f < 4; ++f) {
        s16x8 b = *(const s16x8*)&Bs[f * 16 + lr][kk * 32 + kg * 8];
        acc[f] = __builtin_amdgcn_mfma_f32_16x16x32_bf16(af[kk], b, acc[f], 0, 0, 0);
      }
    }
#pragma unroll
    for (int f = 0; f < 4; ++f) {
      int n = colBase + f * 16 + lr;
      if (n < V_) {
        float ob = out_b[n];
#pragma unroll
        for (int r = 0; r < 4; ++r) runsum[r] += __expf(acc[f][r] + ob);
      }
    }
  }
#pragma unroll
  for (int r = 0; r < 4; ++r) {
    float rs = runsum[r];
    rs += __shfl_xor(rs, 1, 64);
    rs += __shfl_xor(rs, 2, 64);
    rs += __shfl_xor(rs, 4, 64);
    rs += __shfl_xor(rs, 8, 64);
    if (lr == 0) atomicAdd(&sumexp[rowBase + w * 16 + kg * 4 + r], rs);
  }
}

// ---------------- target / EOS logit extraction ----------------
__global__ void k_extract(const b16_t* __restrict__ dec_h, const b16_t* __restrict__ emb_bf,
                          const float* __restrict__ out_b, const int* __restrict__ x_ids,
                          float* __restrict__ tl, float* __restrict__ el) {
  int p = blockIdx.x, lane = threadIdx.x;       // 64 threads
  int t = p >> 3, b = p & 7;
  for (int s = 0; s < S_; ++s) {
    const b16_t* hr = dec_h + ((size_t)p * S_ + s) * D_;
    float hv[4];
#pragma unroll
    for (int j = 0; j < 4; ++j) hv[j] = bf2f(hr[lane * 4 + j]);
    if (s < MS_) {
      int pos = t + s; if (pos > T_ - 1) pos = T_ - 1;
      int tok = x_ids[b * (T_ + 2) + pos + 1];
      const b16_t* er = emb_bf + (size_t)tok * D_;
      float ps = 0.f;
#pragma unroll
      for (int j = 0; j < 4; ++j) ps += hv[j] * bf2f(er[lane * 4 + j]);
      for (int m = 1; m < 64; m <<= 1) ps += __shfl_xor(ps, m, 64);
      if (lane == 0) tl[p * MS_ + s] = ps + out_b[tok];
    }
    if (s >= 1) {
      const b16_t* er = emb_bf + (size_t)EOS_ * D_;
      float ps = 0.f;
#pragma unroll
      for (int j = 0; j < 4; ++j) ps += hv[j] * bf2f(er[lane * 4 + j]);
      for (int m = 1; m < 64; m <<= 1) ps += __shfl_xor(ps, m, 64);
      if (lane == 0) el[p * MS_ + (s - 1)] = ps + out_b[EOS_];
    }
  }
}

// ---------------- final: log-probs, DP, loss ----------------
__global__ __launch_bounds__(256) void k_final(const float* __restrict__ sumexp,
                                               const float* __restrict__ tl,
                                               const float* __restrict__ el,
                                               const int* __restrict__ lens,
                                               float* __restrict__ out) {
  __shared__ float logpy[T_][S_][B_];
  __shared__ float alpha[T_ + 1][B_];
  int tid = threadIdx.x;
  for (int p = tid; p < T_ * B_; p += 256) {
    int t = p >> 3, b = p & 7;
    float lz[S_];
#pragma unroll
    for (int s = 0; s < S_; ++s) lz[s] = __logf(sumexp[p * S_ + s]);
    float cum = 0.f, cums[MS_];
#pragma unroll
    for (int s = 0; s < MS_; ++s) {
      float tlp = tl[p * MS_ + s] - lz[s];
      if (t + s < T_) cum += tlp;
      cums[s] = cum;
    }
#pragma unroll
    for (int k = 1; k <= MS_; ++k) {
      float bv = -1000000.0f;
      if (t + k <= T_) bv = cums[k - 1] + (el[p * MS_ + (k - 1)] - lz[k]);
      logpy[t][k][b] = bv;
    }
  }
  __syncthreads();
  if (tid < B_) {
    int b = tid;
    alpha[0][b] = 0.f;
    for (int j = 1; j <= T_; ++j) {
      float vs[MS_], vmax = -1e30f;
#pragma unroll
      for (int k = 1; k <= MS_; ++k) {
        float vv = -2000000.0f;
        if (j - k >= 0) vv = alpha[j - k][b] + logpy[j - k][k][b];
        vs[k - 1] = vv;
        if (vv > vmax) vmax = vv;
      }
      float ssum = 0.f;
#pragma unroll
      for (int k = 0; k < MS_; ++k) ssum += __expf(vs[k] - vmax);
      alpha[j][b] = vmax + __logf(ssum);
    }
  }
  __syncthreads();
  if (tid == 0) {
    float num = 0.f, den = 0.f;
    for (int b = 0; b < B_; ++b) { num += alpha[lens[b]][b]; den += (float)lens[b]; }
    out[0] = -num / den;
  }
}

// ---------------- host ----------------
extern "C" void kernel_launch(void* const* d_in, const int* in_sizes, int n_in,
                              void* d_out, int out_size, void* d_ws, size_t ws_size,
                              hipStream_t stream) {
  const int* x_ids   = (const int*)d_in[0];
  const int* lens    = (const int*)d_in[1];
  const float* emb   = (const float*)d_in[2];
  const float* y_st  = (const float*)d_in[3];
  const float* cWi   = (const float*)d_in[4];
  const float* cWh   = (const float*)d_in[5];
  const float* cb    = (const float*)d_in[6];
  const float* y0W   = (const float*)d_in[7];
  const float* y0b   = (const float*)d_in[8];
  const float* hlW   = (const float*)d_in[9];
  const float* hlb   = (const float*)d_in[10];
  const float* l0Wi  = (const float*)d_in[11];
  const float* l0Wh  = (const float*)d_in[12];
  const float* l0b   = (const float*)d_in[13];
  const float* l1Wi  = (const float*)d_in[14];
  const float* l1Wh  = (const float*)d_in[15];
  const float* l1b   = (const float*)d_in[16];
  const float* outb  = (const float*)d_in[17];
  float* out = (float*)d_out;
  (void)in_sizes; (void)n_in; (void)out_size; (void)ws_size;

  char* ws = (char*)d_ws;
  size_t cur = 0;
  auto alloc = [&](size_t bytes) { size_t o = cur; cur += (bytes + 255) & ~(size_t)255; return o; };
  b16_t* emb_bf    = (b16_t*)(ws + alloc((size_t)V_ * D_ * 2));
  b16_t* cWi_bf    = (b16_t*)(ws + alloc(1024 * 256 * 2));
  b16_t* y0W_bf    = (b16_t*)(ws + alloc(256 * 256 * 2));
  b16_t* hlW_bf    = (b16_t*)(ws + alloc(512 * 256 * 2));
  b16_t* l0Wi_bf   = (b16_t*)(ws + alloc(1024 * 256 * 2));
  b16_t* l0Wh_bf   = (b16_t*)(ws + alloc(1024 * 256 * 2));
  b16_t* Wcat_bf   = (b16_t*)(ws + alloc(1024 * 512 * 2));
  unsigned* Whf    = (unsigned*)(ws + alloc(1024 * 128 * 4));
  b16_t* x_bf      = (b16_t*)(ws + alloc((size_t)B_ * T_ * D_ * 2));
  b16_t* seq_bf    = (b16_t*)(ws + alloc(1024 * 256 * 2));
  float* encX      = (float*)(ws + alloc((size_t)1024 * 1024 * 4));
  b16_t* droph_bf  = (b16_t*)(ws + alloc(1024 * 256 * 2));
  b16_t* y_in0_bf  = (b16_t*)(ws + alloc(1024 * 256 * 2));
  b16_t* hcat      = (b16_t*)(ws + alloc(1024 * 512 * 2));
  b16_t* seg_bf    = (b16_t*)(ws + alloc((size_t)5120 * 256 * 2));
  float* X0        = (float*)(ws + alloc((size_t)5120 * 1024 * 4));
  float* c0        = (float*)(ws + alloc((size_t)2 * 1024 * 256 * 4));   // c0 then c1
  float* c1        = c0 + 1024 * 256;
  b16_t* dec_h_bf  = (b16_t*)(ws + alloc((size_t)5120 * 256 * 2));
  float* sumexp    = (float*)(ws + alloc(5120 * 4));                     // 20480
  int* flags       = (int*)(ws + alloc(128 * 8 * 4));                    // 4096 (contiguous!)
  unsigned* hglob  = (unsigned*)(ws + alloc((size_t)129 * 8 * 128 * 4)); // slot0 = 4096
  float* tl        = (float*)(ws + alloc(1024 * MS_ * 4));
  float* el        = (float*)(ws + alloc(1024 * MS_ * 4));

  // zero: sumexp(20480) + flags(4096) + hglob slot0(4096) contiguous
  hipMemsetAsync(sumexp, 0, 20480 + 4096 + 4096, stream);
  hipMemsetAsync(c0, 0, (size_t)2 * 1024 * 256 * 4, stream);

  k_prep<<<1024, 256, 0, stream>>>(emb, cWi, y0W, hlW, l0Wi, l0Wh, l1Wi, l1Wh, cWh,
                                   emb_bf, cWi_bf, y0W_bf, hlW_bf, l0Wi_bf, l0Wh_bf,
                                   Wcat_bf, Whf);
  k_gather_x<<<B_ * T_, 256, 0, stream>>>(x_ids, emb, x_bf);
  k_seq<<<1024, 256, 0, stream>>>(x_bf, y_st, seq_bf);

  k_gemm<<<dim3(16, 16), 256, 0, stream>>>(seq_bf, cWi_bf, cb, encX, 1024, 0, 0);
  k_encoder<<<16, 512, 0, stream>>>(Whf, encX, hglob, flags, droph_bf);

  k_gemm<<<dim3(16, 4), 256, 0, stream>>>(droph_bf, y0W_bf, y0b, (float*)y_in0_bf, 256, 0, 1);
  k_gemm<<<dim3(16, 8), 256, 0, stream>>>(droph_bf, hlW_bf, hlb, (float*)hcat, 512, 1, 1);
  k_seg<<<5120, 256, 0, stream>>>(x_bf, y_in0_bf, seg_bf);
  k_gemm<<<dim3(80, 16), 256, 0, stream>>>(seg_bf, l0Wi_bf, l0b, X0, 1024, 0, 0);

  for (int s = 0; s < S_; ++s) {
    k_dec_step<256, 0><<<64, 512, 0, stream>>>(hcat, l0Wh_bf, X0, nullptr, c0, nullptr, s);
    k_dec_step<512, 1><<<64, 512, 0, stream>>>(hcat, Wcat_bf, nullptr, l1b, c1, dec_h_bf, s);
  }

  k_logits<<<dim3(80, 8), 256, 0, stream>>>(dec_h_bf, emb_bf, outb, sumexp);
  k_extract<<<1024, 64, 0, stream>>>(dec_h_bf, emb_bf, outb, x_ids, tl, el);
  k_final<<<1, 256, 0, stream>>>(sumexp, tl, el, lens, out);
}

// Round 3
// 676.782 us; speedup vs baseline: 1.9533x; 1.4665x over previous
//
#include <hip/hip_runtime.h>

#define V_ 10000
#define D_ 256
#define T_ 128
#define B_ 8
#define MS_ 4
#define S_ 5
#define EOS_ 4

typedef unsigned short b16_t;
typedef __attribute__((ext_vector_type(8))) short s16x8;
typedef __attribute__((ext_vector_type(8))) unsigned short u16x8;
typedef __attribute__((ext_vector_type(4))) float f32x4;
typedef __attribute__((ext_vector_type(2))) _Float16 h16x2;

__device__ inline b16_t f2bf(float f) {
  union { float f; unsigned u; } v; v.f = f;
  unsigned r = v.u + 0x7FFFu + ((v.u >> 16) & 1u);
  return (b16_t)(r >> 16);
}
__device__ inline float bf2f(b16_t h) {
  union { unsigned u; float f; } v; v.u = ((unsigned)h) << 16; return v.f;
}
__device__ inline float sigm_(float x) { return 1.0f / (1.0f + __expf(-x)); }
__device__ inline float tanh_(float x) { return 2.0f / (1.0f + __expf(-2.0f * x)) - 1.0f; }
__device__ inline h16x2 bch(unsigned u) { return __builtin_bit_cast(h16x2, u); }
__device__ inline unsigned pkh(float a, float b) {
  h16x2 v; v.x = (_Float16)a; v.y = (_Float16)b;
  return __builtin_bit_cast(unsigned, v);
}

#if __has_builtin(__builtin_amdgcn_fdot2)
#define FDOT2(a, b, c) __builtin_amdgcn_fdot2((a), (b), (c), false)
#else
#define FDOT2(a, b, c) ((c) + (float)(a).x * (float)(b).x + (float)(a).y * (float)(b).y)
#endif

// ---------------- prep: all weight casts + gather + seq in one kernel ----------------
__device__ inline void cvt4(const float* __restrict__ s, b16_t* __restrict__ d) {
  float4 v = *(const float4*)s;
  ushort4 o = { f2bf(v.x), f2bf(v.y), f2bf(v.z), f2bf(v.w) };
  *(ushort4*)d = o;
}

__global__ void k_prep(const float* __restrict__ emb, const float* __restrict__ cWi,
                       const float* __restrict__ y0W, const float* __restrict__ hlW,
                       const float* __restrict__ l0Wi, const float* __restrict__ l0Wh,
                       const float* __restrict__ l1Wi, const float* __restrict__ l1Wh,
                       const float* __restrict__ cWh, const int* __restrict__ x_ids,
                       const float* __restrict__ y_st,
                       b16_t* __restrict__ emb_bf, b16_t* __restrict__ cWi_bf,
                       b16_t* __restrict__ y0W_bf, b16_t* __restrict__ hlW_bf,
                       b16_t* __restrict__ l0Wi_bf, b16_t* __restrict__ l0Wh_bf,
                       b16_t* __restrict__ Wcat_bf, unsigned* __restrict__ Whf,
                       b16_t* __restrict__ x_bf, b16_t* __restrict__ seq_bf) {
  for (long i = (long)blockIdx.x * blockDim.x + threadIdx.x; i < 1213440L;
       i += (long)gridDim.x * blockDim.x) {
    if (i < 640000L) { cvt4(emb + i * 4, emb_bf + i * 4); }
    else if (i < 705536L) { long j = i - 640000L; cvt4(cWi + j * 4, cWi_bf + j * 4); }
    else if (i < 721920L) { long j = i - 705536L; cvt4(y0W + j * 4, y0W_bf + j * 4); }
    else if (i < 754688L) { long j = i - 721920L; cvt4(hlW + j * 4, hlW_bf + j * 4); }
    else if (i < 820224L) { long j = i - 754688L; cvt4(l0Wi + j * 4, l0Wi_bf + j * 4); }
    else if (i < 885760L) { long j = i - 820224L; cvt4(l0Wh + j * 4, l0Wh_bf + j * 4); }
    else if (i < 1016832L) {
      long j = (i - 885760L) * 4;
      long n = j >> 9; int k = (int)(j & 511);
      const float* src = (k < 256) ? (l1Wi + n * 256 + k) : (l1Wh + n * 256 + (k - 256));
      cvt4(src, Wcat_bf + j);
    } else if (i < 1082368L) {
      long j = i - 1016832L;
      float4 v = *(const float4*)(cWh + j * 4);
      Whf[2 * j] = pkh(v.x, v.y);
      Whf[2 * j + 1] = pkh(v.z, v.w);
    } else if (i < 1147904L) {
      long j = i - 1082368L;                    // x_bf: j over [B*T*64)
      int bt = (int)(j >> 6), c = (int)(j & 63) * 4;
      int b = bt >> 7, t = bt & 127;
      int tok = x_ids[b * (T_ + 2) + t + 1];
      cvt4(emb + (size_t)tok * D_ + c, x_bf + (size_t)bt * D_ + c);
    } else {
      long j = i - 1147904L;                    // seq_bf: j over [1024*64)
      int m = (int)(j >> 6), c = (int)(j & 63) * 4;
      int t = m >> 3, b = m & 7;
      const float* src = (t == 0) ? (y_st + c)
                                  : (emb + (size_t)x_ids[b * (T_ + 2) + t] * D_ + c);
      cvt4(src, seq_bf + (size_t)m * D_ + c);
    }
  }
}

// ---------------- generic bf16 MFMA GEMM: C[M][N] = A[M][256] @ Bw[N][256]^T ----------------
__global__ __launch_bounds__(256) void k_gemm(const b16_t* __restrict__ A,
                                              const b16_t* __restrict__ Bw,
                                              const float* __restrict__ bias,
                                              float* __restrict__ C,
                                              int N, int act, int obf) {
  __shared__ b16_t As[64][264];
  __shared__ b16_t Bs[64][264];
  int tid = threadIdx.x;
  int rowBase = blockIdx.x * 64, colBase = blockIdx.y * 64;
  for (int i = tid; i < 64 * 32; i += 256) {
    int r = i >> 5, c = (i & 31) * 8;
    *(u16x8*)&As[r][c] = *(const u16x8*)(A + (size_t)(rowBase + r) * D_ + c);
    *(u16x8*)&Bs[r][c] = *(const u16x8*)(Bw + (size_t)(colBase + r) * D_ + c);
  }
  __syncthreads();
  int w = tid >> 6, l = tid & 63, lr = l & 15, kg = l >> 4;
  f32x4 acc[4] = {{0.f,0.f,0.f,0.f},{0.f,0.f,0.f,0.f},{0.f,0.f,0.f,0.f},{0.f,0.f,0.f,0.f}};
  for (int kk = 0; kk < 8; ++kk) {
    s16x8 a = *(const s16x8*)&As[w * 16 + lr][kk * 32 + kg * 8];
#pragma unroll
    for (int f = 0; f < 4; ++f) {
      s16x8 b = *(const s16x8*)&Bs[f * 16 + lr][kk * 32 + kg * 8];
      acc[f] = __builtin_amdgcn_mfma_f32_16x16x32_bf16(a, b, acc[f], 0, 0, 0);
    }
  }
#pragma unroll
  for (int f = 0; f < 4; ++f) {
#pragma unroll
    for (int r = 0; r < 4; ++r) {
      int m = rowBase + w * 16 + kg * 4 + r;
      int n = colBase + f * 16 + lr;
      float v = acc[f][r];
      if (bias) v += bias[n];
      if (act == 1) v = tanh_(v);
      size_t idx = (size_t)m * N + n;
      if (obf) ((b16_t*)C)[idx] = f2bf(v); else C[idx] = v;
    }
  }
}

// ---------------- persistent encoder v2: 16 blocks = 8 batches x 2 halves ----------------
// thread: dim_local = tid>>2 (0..127), gate = tid&3; row = gate*256 + half*128 + dim_local
// weights pinned in VGPRs; h double-buffered in LDS; wave0 = producer, wave1 = consumer.
__global__ __launch_bounds__(512, 2) void k_encoder(
    const unsigned* __restrict__ Whf,   // [1024][128] f16-pair packed
    const float* __restrict__ encX,     // [1024][1024] (seq@Wi^T + b)
    unsigned* __restrict__ hglob,       // [129][8][128] dwords of f16 pairs
    int* __restrict__ flags,            // [129][8][2] zeroed
    b16_t* __restrict__ droph) {        // [1024][256] bf16 of 0.1*h
  int batch = blockIdx.x & 7, half = blockIdx.x >> 3;
  int tid = threadIdx.x;
  int gate = tid & 3, dl = tid >> 2;          // dl in [0,128)
  int dim = half * 128 + dl;
  int row = gate * 256 + dim;
  unsigned wv[128];
  {
    const uint4* wp = (const uint4*)(Whf + (size_t)row * 128);
#pragma unroll
    for (int i = 0; i < 32; ++i) {
      uint4 v = wp[i];
      wv[4 * i + 0] = v.x; wv[4 * i + 1] = v.y;
      wv[4 * i + 2] = v.z; wv[4 * i + 3] = v.w;
    }
  }
#pragma unroll
  for (int i = 0; i < 128; ++i) asm volatile("" : "+v"(wv[i]));

  __shared__ unsigned hbuf[2][128];
  if (tid < 256) ((unsigned*)hbuf)[tid] = 0;
  __syncthreads();

  float c = 0.f;
  int p = 0;
#pragma unroll 1
  for (int t = 0; t < 128; ++t) {
    float a = encX[((size_t)t * 8 + batch) * 1024 + row];
    uint4 hv[8];
#pragma unroll
    for (int i = 0; i < 8; ++i) hv[i] = *(const uint4*)&hbuf[p][i * 4];
    float s0 = 0.f, s1 = 0.f, s2 = 0.f, s3 = 0.f;
#pragma unroll
    for (int i = 0; i < 8; ++i) {
      s0 = FDOT2(bch(hv[i].x), bch(wv[4 * i + 0]), s0);
      s1 = FDOT2(bch(hv[i].y), bch(wv[4 * i + 1]), s1);
      s2 = FDOT2(bch(hv[i].z), bch(wv[4 * i + 2]), s2);
      s3 = FDOT2(bch(hv[i].w), bch(wv[4 * i + 3]), s3);
    }
    float acc = a + (s0 + s1) + (s2 + s3);
    int base = (tid & 63) & ~3;
    float gi = __shfl(acc, base + 0, 64);
    float gf = __shfl(acc, base + 1, 64);
    float gg = __shfl(acc, base + 2, 64);
    float go = __shfl(acc, base + 3, 64);
    float c2 = sigm_(gf) * c + sigm_(gi) * tanh_(gg);
    float h2 = sigm_(go) * tanh_(c2);
    c = c2;
    int q = p ^ 1;
    if (gate == 0) {
      ((_Float16*)hbuf[q])[dim] = (_Float16)h2;
      droph[((size_t)t * 8 + batch) * 256 + dim] = f2bf(0.1f * h2);
    }
    __syncthreads();                       // local halfwords of h_{t+1} visible
    if (t < 127) {
      if (tid < 64) {                      // wave0: publish local half
        unsigned dw = hbuf[q][half * 64 + tid];
        __hip_atomic_store(&hglob[((size_t)(t + 1) * 8 + batch) * 128 + half * 64 + tid],
                           dw, __ATOMIC_RELAXED, __HIP_MEMORY_SCOPE_AGENT);
        asm volatile("s_waitcnt vmcnt(0)" ::: "memory");
        if (tid == 0)
          __hip_atomic_store(&flags[((t + 1) * 8 + batch) * 2 + half], 1,
                             __ATOMIC_RELAXED, __HIP_MEMORY_SCOPE_AGENT);
      } else if (tid < 128) {              // wave1: fetch remote half
        int lane = tid - 64;
        int* fp = &flags[((t + 1) * 8 + batch) * 2 + (1 - half)];
        while (__hip_atomic_load(fp, __ATOMIC_RELAXED, __HIP_MEMORY_SCOPE_AGENT) == 0)
          __builtin_amdgcn_s_sleep(1);
        asm volatile("" ::: "memory");
        unsigned dw = __hip_atomic_load(
            &hglob[((size_t)(t + 1) * 8 + batch) * 128 + (1 - half) * 64 + lane],
            __ATOMIC_RELAXED, __HIP_MEMORY_SCOPE_AGENT);
        hbuf[q][(1 - half) * 64 + lane] = dw;
      }
    }
    __syncthreads();                       // hbuf[q] = full h_{t+1}
    p = q;
  }
}

// ---------------- seg build ----------------
__global__ void k_seg(const b16_t* __restrict__ x_bf, const b16_t* __restrict__ y_in0_bf,
                      b16_t* __restrict__ seg_bf) {
  int ps = blockIdx.x, d = threadIdx.x;         // ps = p*S + s
  int p = ps / S_, s = ps % S_;
  int t = p >> 3, b = p & 7;
  b16_t v;
  if (s == 0) v = y_in0_bf[(size_t)p * D_ + d];
  else {
    int tt = t + s - 1;
    v = (tt < T_) ? x_bf[((size_t)b * T_ + tt) * D_ + d] : (b16_t)0;
  }
  seg_bf[(size_t)ps * D_ + d] = v;
}

// ---------------- fused decoder step: full-row gates GEMM + LSTM cell ----------------
template <int K, int PHASE>
__global__ __launch_bounds__(512, 2) void k_dec_step(
    b16_t* __restrict__ hcat,           // [1024][512] : [h0 | h1] bf16
    const b16_t* __restrict__ Wbf,      // [1024][K]
    const float* __restrict__ X0,       // phase0: [5120][1024], else null
    const float* __restrict__ bias,     // phase1: l1_b
    float* __restrict__ cst,            // c state [1024][256]
    b16_t* __restrict__ dec_out,        // phase1: dec_h [5120][256]
    int s) {
  __shared__ b16_t As[16][(K == 256) ? 264 : 520];
  __shared__ float gacc[16][1028];
  int tid = threadIdx.x;
  int R0 = blockIdx.x * 16;
  constexpr int CH = K / 8;
  for (int i = tid; i < 16 * CH; i += 512) {
    int r = i / CH, cc = (i % CH) * 8;
    *(u16x8*)&As[r][cc] = *(const u16x8*)(hcat + (size_t)(R0 + r) * 512 + cc);
  }
  __syncthreads();
  int w = tid >> 6, l = tid & 63, lr = l & 15, kg = l >> 4;
  int g = w >> 1, ch = w & 1;
  constexpr int NK = K / 32;
  s16x8 af[NK];
#pragma unroll
  for (int kk = 0; kk < NK; ++kk) af[kk] = *(const s16x8*)&As[lr][kk * 32 + kg * 8];
  int ncol0 = g * 256 + ch * 128;
  f32x4 acc[8];
#pragma unroll
  for (int nt = 0; nt < 8; ++nt) acc[nt] = f32x4{0.f, 0.f, 0.f, 0.f};
#pragma unroll
  for (int nt = 0; nt < 8; ++nt) {
    int n = ncol0 + nt * 16 + lr;
    const b16_t* bp = Wbf + (size_t)n * K + kg * 8;
#pragma unroll
    for (int kk = 0; kk < NK; ++kk) {
      s16x8 bf = *(const s16x8*)(bp + kk * 32);
      acc[nt] = __builtin_amdgcn_mfma_f32_16x16x32_bf16(af[kk], bf, acc[nt], 0, 0, 0);
    }
  }
#pragma unroll
  for (int nt = 0; nt < 8; ++nt)
#pragma unroll
    for (int r = 0; r < 4; ++r)
      gacc[kg * 4 + r][ncol0 + nt * 16 + lr] = acc[nt][r];
  __syncthreads();
  int rr = tid >> 5, dq = tid & 31;
  int pidx = R0 + rr;
#pragma unroll
  for (int u = 0; u < 8; ++u) {
    int d = u * 32 + dq;
    float gi = gacc[rr][d], gf = gacc[rr][256 + d];
    float gg = gacc[rr][512 + d], go = gacc[rr][768 + d];
    if (PHASE == 0) {
      const float* xp = X0 + ((size_t)pidx * 5 + s) * 1024;
      gi += xp[d]; gf += xp[256 + d]; gg += xp[512 + d]; go += xp[768 + d];
    } else {
      gi += bias[d]; gf += bias[256 + d]; gg += bias[512 + d]; go += bias[768 + d];
    }
    float c = cst[(size_t)pidx * 256 + d];
    float c2 = sigm_(gf) * c + sigm_(gi) * tanh_(gg);
    float h2 = sigm_(go) * tanh_(c2);
    cst[(size_t)pidx * 256 + d] = c2;
    b16_t hb = f2bf(h2);
    if (PHASE == 0) hcat[(size_t)pidx * 512 + d] = hb;
    else {
      hcat[(size_t)pidx * 512 + 256 + d] = hb;
      dec_out[((size_t)pidx * 5 + s) * 256 + d] = hb;
    }
  }
}

// ---------------- logits + fused sum(exp): M=128 tiles, A-frags in regs ----------------
__global__ __launch_bounds__(512) void k_logits(const b16_t* __restrict__ Abf,
                                                const b16_t* __restrict__ emb_bf,
                                                const float* __restrict__ out_b,
                                                float* __restrict__ sumexp) {
  __shared__ b16_t Bs[64][264];
  int tid = threadIdx.x;
  int rowBase = blockIdx.x * 128;             // 40 row blocks
  int w = tid >> 6, l = tid & 63, lr = l & 15, kg = l >> 4;
  s16x8 af[8];
  {
    const b16_t* arow = Abf + (size_t)(rowBase + w * 16 + lr) * 256;
#pragma unroll
    for (int kk = 0; kk < 8; ++kk) af[kk] = *(const s16x8*)(arow + kk * 32 + kg * 8);
  }
  float runsum[4] = {0.f, 0.f, 0.f, 0.f};
  int t0 = blockIdx.y * 23, t1 = (t0 + 23 < 157) ? (t0 + 23) : 157;
  for (int tile = t0; tile < t1; ++tile) {
    int colBase = tile * 64;
    __syncthreads();
    for (int i = tid; i < 64 * 32; i += 512) {
      int r = i >> 5, cc = (i & 31) * 8;
      int vrow = colBase + r;
      u16x8 bv = {0, 0, 0, 0, 0, 0, 0, 0};
      if (vrow < V_) bv = *(const u16x8*)(emb_bf + (size_t)vrow * D_ + cc);
      *(u16x8*)&Bs[r][cc] = bv;
    }
    __syncthreads();
    f32x4 acc[4] = {{0.f,0.f,0.f,0.f},{0.f,0.f,0.f,0.f},{0.f,0.f,0.f,0.f},{0.f,0.f,0.f,0.f}};
#pragma unroll
    for (int kk = 0; kk < 8; ++kk) {
#pragma unroll
      for (int f = 0; f < 4; ++f) {
        s16x8 b = *(const s16x8*)&Bs[f * 16 + lr][kk * 32 + kg * 8];
        acc[f] = __builtin_amdgcn_mfma_f32_16x16x32_bf16(af[kk], b, acc[f], 0, 0, 0);
      }
    }
#pragma unroll
    for (int f = 0; f < 4; ++f) {
      int n = colBase + f * 16 + lr;
      if (n < V_) {
        float ob = out_b[n];
#pragma unroll
        for (int r = 0; r < 4; ++r) runsum[r] += __expf(acc[f][r] + ob);
      }
    }
  }
#pragma unroll
  for (int r = 0; r < 4; ++r) {
    float rs = runsum[r];
    rs += __shfl_xor(rs, 1, 64);
    rs += __shfl_xor(rs, 2, 64);
    rs += __shfl_xor(rs, 4, 64);
    rs += __shfl_xor(rs, 8, 64);
    if (lr == 0) atomicAdd(&sumexp[rowBase + w * 16 + kg * 4 + r], rs);
  }
}

// ---------------- target / EOS logit extraction ----------------
__global__ void k_extract(const b16_t* __restrict__ dec_h, const b16_t* __restrict__ emb_bf,
                          const float* __restrict__ out_b, const int* __restrict__ x_ids,
                          float* __restrict__ tl, float* __restrict__ el) {
  int p = blockIdx.x, lane = threadIdx.x;       // 64 threads
  int t = p >> 3, b = p & 7;
  for (int s = 0; s < S_; ++s) {
    const b16_t* hr = dec_h + ((size_t)p * S_ + s) * D_;
    float hv[4];
#pragma unroll
    for (int j = 0; j < 4; ++j) hv[j] = bf2f(hr[lane * 4 + j]);
    if (s < MS_) {
      int pos = t + s; if (pos > T_ - 1) pos = T_ - 1;
      int tok = x_ids[b * (T_ + 2) + pos + 1];
      const b16_t* er = emb_bf + (size_t)tok * D_;
      float ps = 0.f;
#pragma unroll
      for (int j = 0; j < 4; ++j) ps += hv[j] * bf2f(er[lane * 4 + j]);
      for (int m = 1; m < 64; m <<= 1) ps += __shfl_xor(ps, m, 64);
      if (lane == 0) tl[p * MS_ + s] = ps + out_b[tok];
    }
    if (s >= 1) {
      const b16_t* er = emb_bf + (size_t)EOS_ * D_;
      float ps = 0.f;
#pragma unroll
      for (int j = 0; j < 4; ++j) ps += hv[j] * bf2f(er[lane * 4 + j]);
      for (int m = 1; m < 64; m <<= 1) ps += __shfl_xor(ps, m, 64);
      if (lane == 0) el[p * MS_ + (s - 1)] = ps + out_b[EOS_];
    }
  }
}

// ---------------- final: log-probs, DP, loss ----------------
__global__ __launch_bounds__(256) void k_final(const float* __restrict__ sumexp,
                                               const float* __restrict__ tl,
                                               const float* __restrict__ el,
                                               const int* __restrict__ lens,
                                               float* __restrict__ out) {
  __shared__ float logpy[T_][S_][B_];
  __shared__ float alpha[T_ + 1][B_];
  int tid = threadIdx.x;
  for (int p = tid; p < T_ * B_; p += 256) {
    int t = p >> 3, b = p & 7;
    float lz[S_];
#pragma unroll
    for (int s = 0; s < S_; ++s) lz[s] = __logf(sumexp[p * S_ + s]);
    float cum = 0.f, cums[MS_];
#pragma unroll
    for (int s = 0; s < MS_; ++s) {
      float tlp = tl[p * MS_ + s] - lz[s];
      if (t + s < T_) cum += tlp;
      cums[s] = cum;
    }
#pragma unroll
    for (int k = 1; k <= MS_; ++k) {
      float bv = -1000000.0f;
      if (t + k <= T_) bv = cums[k - 1] + (el[p * MS_ + (k - 1)] - lz[k]);
      logpy[t][k][b] = bv;
    }
  }
  __syncthreads();
  if (tid < B_) {
    int b = tid;
    alpha[0][b] = 0.f;
    for (int j = 1; j <= T_; ++j) {
      float vs[MS_], vmax = -1e30f;
#pragma unroll
      for (int k = 1; k <= MS_; ++k) {
        float vv = -2000000.0f;
        if (j - k >= 0) vv = alpha[j - k][b] + logpy[j - k][k][b];
        vs[k - 1] = vv;
        if (vv > vmax) vmax = vv;
      }
      float ssum = 0.f;
#pragma unroll
      for (int k = 0; k < MS_; ++k) ssum += __expf(vs[k] - vmax);
      alpha[j][b] = vmax + __logf(ssum);
    }
  }
  __syncthreads();
  if (tid == 0) {
    float num = 0.f, den = 0.f;
    for (int b = 0; b < B_; ++b) { num += alpha[lens[b]][b]; den += (float)lens[b]; }
    out[0] = -num / den;
  }
}

// ---------------- host ----------------
extern "C" void kernel_launch(void* const* d_in, const int* in_sizes, int n_in,
                              void* d_out, int out_size, void* d_ws, size_t ws_size,
                              hipStream_t stream) {
  const int* x_ids   = (const int*)d_in[0];
  const int* lens    = (const int*)d_in[1];
  const float* emb   = (const float*)d_in[2];
  const float* y_st  = (const float*)d_in[3];
  const float* cWi   = (const float*)d_in[4];
  const float* cWh   = (const float*)d_in[5];
  const float* cb    = (const float*)d_in[6];
  const float* y0W   = (const float*)d_in[7];
  const float* y0b   = (const float*)d_in[8];
  const float* hlW   = (const float*)d_in[9];
  const float* hlb   = (const float*)d_in[10];
  const float* l0Wi  = (const float*)d_in[11];
  const float* l0Wh  = (const float*)d_in[12];
  const float* l0b   = (const float*)d_in[13];
  const float* l1Wi  = (const float*)d_in[14];
  const float* l1Wh  = (const float*)d_in[15];
  const float* l1b   = (const float*)d_in[16];
  const float* outb  = (const float*)d_in[17];
  float* out = (float*)d_out;
  (void)in_sizes; (void)n_in; (void)out_size; (void)ws_size;

  char* ws = (char*)d_ws;
  size_t cur = 0;
  auto alloc = [&](size_t bytes) { size_t o = cur; cur += (bytes + 255) & ~(size_t)255; return o; };
  b16_t* emb_bf    = (b16_t*)(ws + alloc((size_t)V_ * D_ * 2));
  b16_t* cWi_bf    = (b16_t*)(ws + alloc(1024 * 256 * 2));
  b16_t* y0W_bf    = (b16_t*)(ws + alloc(256 * 256 * 2));
  b16_t* hlW_bf    = (b16_t*)(ws + alloc(512 * 256 * 2));
  b16_t* l0Wi_bf   = (b16_t*)(ws + alloc(1024 * 256 * 2));
  b16_t* l0Wh_bf   = (b16_t*)(ws + alloc(1024 * 256 * 2));
  b16_t* Wcat_bf   = (b16_t*)(ws + alloc(1024 * 512 * 2));
  unsigned* Whf    = (unsigned*)(ws + alloc(1024 * 128 * 4));
  b16_t* x_bf      = (b16_t*)(ws + alloc((size_t)B_ * T_ * D_ * 2));
  b16_t* seq_bf    = (b16_t*)(ws + alloc(1024 * 256 * 2));
  float* encX      = (float*)(ws + alloc((size_t)1024 * 1024 * 4));
  b16_t* droph_bf  = (b16_t*)(ws + alloc(1024 * 256 * 2));
  b16_t* y_in0_bf  = (b16_t*)(ws + alloc(1024 * 256 * 2));
  b16_t* hcat      = (b16_t*)(ws + alloc(1024 * 512 * 2));
  b16_t* seg_bf    = (b16_t*)(ws + alloc((size_t)5120 * 256 * 2));
  float* X0        = (float*)(ws + alloc((size_t)5120 * 1024 * 4));
  float* c0        = (float*)(ws + alloc((size_t)2 * 1024 * 256 * 4));
  float* c1        = c0 + 1024 * 256;
  b16_t* dec_h_bf  = (b16_t*)(ws + alloc((size_t)5120 * 256 * 2));
  float* sumexp    = (float*)(ws + alloc(5120 * 4));                     // 20480 B
  int* flags       = (int*)(ws + alloc(129 * 8 * 2 * 4));                // 8256 B, contiguous after sumexp
  unsigned* hglob  = (unsigned*)(ws + alloc((size_t)129 * 8 * 128 * 4));
  float* tl        = (float*)(ws + alloc(1024 * MS_ * 4));
  float* el        = (float*)(ws + alloc(1024 * MS_ * 4));

  hipMemsetAsync(sumexp, 0, 20480 + 8256, stream);       // sumexp + flags
  hipMemsetAsync(c0, 0, (size_t)2 * 1024 * 256 * 4, stream);

  k_prep<<<1024, 256, 0, stream>>>(emb, cWi, y0W, hlW, l0Wi, l0Wh, l1Wi, l1Wh, cWh,
                                   x_ids, y_st,
                                   emb_bf, cWi_bf, y0W_bf, hlW_bf, l0Wi_bf, l0Wh_bf,
                                   Wcat_bf, Whf, x_bf, seq_bf);

  k_gemm<<<dim3(16, 16), 256, 0, stream>>>(seq_bf, cWi_bf, cb, encX, 1024, 0, 0);
  k_encoder<<<16, 512, 0, stream>>>(Whf, encX, hglob, flags, droph_bf);

  k_gemm<<<dim3(16, 4), 256, 0, stream>>>(droph_bf, y0W_bf, y0b, (float*)y_in0_bf, 256, 0, 1);
  k_gemm<<<dim3(16, 8), 256, 0, stream>>>(droph_bf, hlW_bf, hlb, (float*)hcat, 512, 1, 1);
  k_seg<<<5120, 256, 0, stream>>>(x_bf, y_in0_bf, seg_bf);
  k_gemm<<<dim3(80, 16), 256, 0, stream>>>(seg_bf, l0Wi_bf, l0b, X0, 1024, 0, 0);

  for (int s = 0; s < S_; ++s) {
    k_dec_step<256, 0><<<64, 512, 0, stream>>>(hcat, l0Wh_bf, X0, nullptr, c0, nullptr, s);
    k_dec_step<512, 1><<<64, 512, 0, stream>>>(hcat, Wcat_bf, nullptr, l1b, c1, dec_h_bf, s);
  }

  k_logits<<<dim3(40, 7), 512, 0, stream>>>(dec_h_bf, emb_bf, outb, sumexp);
  k_extract<<<1024, 64, 0, stream>>>(dec_h_bf, emb_bf, outb, x_ids, tl, el);
  k_final<<<1, 256, 0, stream>>>(sumexp, tl, el, lens, out);
}